// Round 1
// baseline (793.254 us; speedup 1.0000x reference)
//
#include <hip/hip_runtime.h>
#include <math.h>

// ---------------------------------------------------------------------------
// GCN: h1 = relu(norm_agg(x@W1)+b1); h2 = norm_agg(h1@W2)+b2;
//      g = mean_pool(h2, batch); out = relu(g@W3+b3)@W4 + b4
// norm_agg(h)[d] = sum_{e: dst=d} h[src_e]*dinv[src]*dinv[d] + h[d]*dinv[d]^2
// deg[d] = in-degree + 1 (self loop), dinv = 1/sqrt(deg)
// Strategy: build CSR once (count -> scan -> place), gather-aggregate (no fp32
// scatter atomics), fuse pooling into layer-2 aggregation.
// ---------------------------------------------------------------------------

__global__ __launch_bounds__(256) void k_zero(int* cnt, float* gsum, float* gcnt,
                                              int n, int gsz, int ng) {
  int i = blockIdx.x * 256 + threadIdx.x;
  if (i < n) cnt[i] = 0;
  if (i < gsz) gsum[i] = 0.f;
  if (i < ng) gcnt[i] = 0.f;
}

__global__ __launch_bounds__(256) void k_count(const int* __restrict__ dst,
                                               int* __restrict__ cnt, int e) {
  int i = blockIdx.x * 256 + threadIdx.x;
  if (i < e) atomicAdd(&cnt[dst[i]], 1);
}

// Exclusive scan, level A: each block scans a 1024-element chunk.
__global__ __launch_bounds__(256) void k_scanA(const int* __restrict__ cnt,
                                               int* __restrict__ startArr,
                                               int* __restrict__ bsum, int n) {
  __shared__ int sh[256];
  int t = threadIdx.x, b = blockIdx.x;
  int base = b * 1024 + t * 4;
  int v0 = 0, v1 = 0, v2 = 0, v3 = 0;
  if (base + 3 < n) {
    int4 v = *(const int4*)&cnt[base];
    v0 = v.x; v1 = v.y; v2 = v.z; v3 = v.w;
  } else {
    if (base + 0 < n) v0 = cnt[base + 0];
    if (base + 1 < n) v1 = cnt[base + 1];
    if (base + 2 < n) v2 = cnt[base + 2];
  }
  int local = v0 + v1 + v2 + v3;
  sh[t] = local;
  __syncthreads();
  for (int off = 1; off < 256; off <<= 1) {
    int x = (t >= off) ? sh[t - off] : 0;
    __syncthreads();
    sh[t] += x;
    __syncthreads();
  }
  int excl = sh[t] - local;
  if (t == 255) bsum[b] = sh[255];
  if (base + 0 < n) startArr[base + 0] = excl;
  if (base + 1 < n) startArr[base + 1] = excl + v0;
  if (base + 2 < n) startArr[base + 2] = excl + v0 + v1;
  if (base + 3 < n) startArr[base + 3] = excl + v0 + v1 + v2;
}

// Level B: single block scans the (<=256) chunk totals, in place, exclusive.
__global__ __launch_bounds__(256) void k_scanB(int* __restrict__ bsum, int nb) {
  __shared__ int sh[256];
  int t = threadIdx.x;
  int v = (t < nb) ? bsum[t] : 0;
  sh[t] = v;
  __syncthreads();
  for (int off = 1; off < 256; off <<= 1) {
    int x = (t >= off) ? sh[t - off] : 0;
    __syncthreads();
    sh[t] += x;
    __syncthreads();
  }
  if (t < nb) bsum[t] = sh[t] - v;
}

// Level C: add chunk offsets; init cursor; compute dinv = 1/sqrt(deg+1).
__global__ __launch_bounds__(256) void k_scanC(int* __restrict__ startArr,
                                               int* __restrict__ cursor,
                                               const int* __restrict__ bsum,
                                               const int* __restrict__ cnt,
                                               float* __restrict__ dinv, int n) {
  int i = blockIdx.x * 256 + threadIdx.x;
  if (i >= n) return;
  int s = startArr[i] + bsum[i >> 10];
  startArr[i] = s;
  cursor[i] = s;
  dinv[i] = 1.0f / sqrtf((float)(cnt[i] + 1));
}

__global__ __launch_bounds__(256) void k_place(const int* __restrict__ src,
                                               const int* __restrict__ dst,
                                               int* __restrict__ cursor,
                                               int* __restrict__ csr, int e) {
  int i = blockIdx.x * 256 + threadIdx.x;
  if (i >= e) return;
  int d = dst[i];
  int pos = atomicAdd(&cursor[d], 1);
  csr[pos] = src[i];
}

// Y[N,64] = X[N,64] @ W[64,64].  64-row tiles; W + X tile in LDS.
// Thread t: rows rb..rb+3 (rb=(t>>4)*4), cols c4..c4+3 (c4=(t&15)*4).
__global__ __launch_bounds__(256) void k_gemm64(const float* __restrict__ X,
                                                const float* __restrict__ W,
                                                float* __restrict__ Y, int n) {
  __shared__ float Xs[64 * 65];
  __shared__ float Ws[64 * 64];
  int t = threadIdx.x;
  int r0 = blockIdx.x << 6;
  for (int i = t * 4; i < 4096; i += 1024)
    *(float4*)&Ws[i] = *(const float4*)&W[i];
  for (int s = t; s < 1024; s += 256) {
    int r = s >> 4, c4 = (s & 15) << 2;
    float4 v = make_float4(0.f, 0.f, 0.f, 0.f);
    if (r0 + r < n) v = *(const float4*)&X[(size_t)(r0 + r) * 64 + c4];
    Xs[r * 65 + c4 + 0] = v.x;
    Xs[r * 65 + c4 + 1] = v.y;
    Xs[r * 65 + c4 + 2] = v.z;
    Xs[r * 65 + c4 + 3] = v.w;
  }
  __syncthreads();
  int c4 = (t & 15) << 2;
  int rb = (t >> 4) << 2;
  float4 a0 = {0, 0, 0, 0}, a1 = {0, 0, 0, 0}, a2 = {0, 0, 0, 0}, a3 = {0, 0, 0, 0};
  for (int k = 0; k < 64; ++k) {
    float4 w = *(const float4*)&Ws[k * 64 + c4];
    float x0 = Xs[(rb + 0) * 65 + k];
    float x1 = Xs[(rb + 1) * 65 + k];
    float x2 = Xs[(rb + 2) * 65 + k];
    float x3 = Xs[(rb + 3) * 65 + k];
    a0.x += x0 * w.x; a0.y += x0 * w.y; a0.z += x0 * w.z; a0.w += x0 * w.w;
    a1.x += x1 * w.x; a1.y += x1 * w.y; a1.z += x1 * w.z; a1.w += x1 * w.w;
    a2.x += x2 * w.x; a2.y += x2 * w.y; a2.z += x2 * w.z; a2.w += x2 * w.w;
    a3.x += x3 * w.x; a3.y += x3 * w.y; a3.z += x3 * w.z; a3.w += x3 * w.w;
  }
  if (r0 + rb + 0 < n) *(float4*)&Y[(size_t)(r0 + rb + 0) * 64 + c4] = a0;
  if (r0 + rb + 1 < n) *(float4*)&Y[(size_t)(r0 + rb + 1) * 64 + c4] = a1;
  if (r0 + rb + 2 < n) *(float4*)&Y[(size_t)(r0 + rb + 2) * 64 + c4] = a2;
  if (r0 + rb + 3 < n) *(float4*)&Y[(size_t)(r0 + rb + 3) * 64 + c4] = a3;
}

// Layer-1 aggregation: one wave per node, lane = feature; out = relu(agg + b).
__global__ __launch_bounds__(256) void k_agg_relu(
    const float* __restrict__ H, const int* __restrict__ csr,
    const int* __restrict__ startArr, const int* __restrict__ cnt,
    const float* __restrict__ dinv, const float* __restrict__ bias,
    float* __restrict__ out, int n) {
  int wid = (blockIdx.x * 256 + threadIdx.x) >> 6;
  int lane = threadIdx.x & 63;
  if (wid >= n) return;
  float dn = dinv[wid];
  float acc = H[(size_t)wid * 64 + lane] * dn * dn;
  int p0 = startArr[wid];
  int c = cnt[wid];
  for (int p = p0; p < p0 + c; ++p) {
    int s = csr[p];
    float w = dinv[s] * dn;
    acc += H[(size_t)s * 64 + lane] * w;
  }
  acc += bias[lane];
  out[(size_t)wid * 64 + lane] = fmaxf(acc, 0.f);
}

// Layer-2 aggregation fused with mean-pool accumulation.
__global__ __launch_bounds__(256) void k_agg_pool(
    const float* __restrict__ H, const int* __restrict__ csr,
    const int* __restrict__ startArr, const int* __restrict__ cnt,
    const float* __restrict__ dinv, const float* __restrict__ bias,
    const int* __restrict__ batch, float* __restrict__ gsum,
    float* __restrict__ gcnt, int n) {
  int wid = (blockIdx.x * 256 + threadIdx.x) >> 6;
  int lane = threadIdx.x & 63;
  if (wid >= n) return;
  float dn = dinv[wid];
  float acc = H[(size_t)wid * 64 + lane] * dn * dn;
  int p0 = startArr[wid];
  int c = cnt[wid];
  for (int p = p0; p < p0 + c; ++p) {
    int s = csr[p];
    float w = dinv[s] * dn;
    acc += H[(size_t)s * 64 + lane] * w;
  }
  acc += bias[lane];
  int g = batch[wid];
  atomicAdd(&gsum[(size_t)g * 64 + lane], acc);
  if (lane == 0) atomicAdd(&gcnt[g], 1.0f);
}

// Head: per-graph wave: m = gsum/max(cnt,1); t = relu(m@W3+b3); out = t.W4+b4
__global__ __launch_bounds__(256) void k_head(
    const float* __restrict__ gsum, const float* __restrict__ gcnt,
    const float* __restrict__ W3, const float* __restrict__ b3,
    const float* __restrict__ W4, const float* __restrict__ b4,
    float* __restrict__ out, int ng) {
  int wid = (blockIdx.x * 256 + threadIdx.x) >> 6;
  int lane = threadIdx.x & 63;
  if (wid >= ng) return;
  float cden = fmaxf(gcnt[wid], 1.0f);
  float m = gsum[(size_t)wid * 64 + lane] / cden;
  float acc = b3[lane];
  for (int k = 0; k < 64; ++k) {
    float mk = __shfl(m, k);
    acc += mk * W3[k * 64 + lane];
  }
  acc = fmaxf(acc, 0.f);
  float r = acc * W4[lane];
  for (int off = 32; off; off >>= 1) r += __shfl_down(r, off);
  if (lane == 0) out[wid] = r + b4[0];
}

extern "C" void kernel_launch(void* const* d_in, const int* in_sizes, int n_in,
                              void* d_out, int out_size, void* d_ws, size_t ws_size,
                              hipStream_t stream) {
  const float* x = (const float*)d_in[0];
  const int* edge = (const int*)d_in[1];   // [2, E] int32
  const int* batch = (const int*)d_in[2];  // [N] int32, sorted
  const float* W1 = (const float*)d_in[3];
  const float* b1 = (const float*)d_in[4];
  const float* W2 = (const float*)d_in[5];
  const float* b2 = (const float*)d_in[6];
  const float* W3 = (const float*)d_in[7];
  const float* b3 = (const float*)d_in[8];
  const float* W4 = (const float*)d_in[9];
  const float* b4 = (const float*)d_in[10];
  float* out = (float*)d_out;

  const int n = in_sizes[0] / 64;   // 100000
  const int e = in_sizes[1] / 2;    // 1600000
  const int ng = out_size;          // 512
  const int* src = edge;
  const int* dst = edge + e;

  // Workspace layout (~59.4 MB total).
  char* ws = (char*)d_ws;
  size_t off = 0;
  auto alloc = [&](size_t bytes) -> void* {
    void* p = ws + off;
    off = (off + bytes + 255) & ~(size_t)255;
    return p;
  };
  float* A = (float*)alloc((size_t)n * 64 * 4);      // h (gemm output)
  float* B = (float*)alloc((size_t)n * 64 * 4);      // aggregated
  float* dinv = (float*)alloc((size_t)n * 4);
  int* cnt = (int*)alloc((size_t)n * 4);
  int* startArr = (int*)alloc((size_t)n * 4);
  int* cursor = (int*)alloc((size_t)n * 4);
  int* bsum = (int*)alloc(1024);
  int* csr = (int*)alloc((size_t)e * 4);
  float* gsum = (float*)alloc((size_t)ng * 64 * 4);
  float* gcnt = (float*)alloc((size_t)ng * 4);

  const int nb = (n + 1023) / 1024;  // scan chunks (98)

  int zmax = n;
  if (ng * 64 > zmax) zmax = ng * 64;
  k_zero<<<(zmax + 255) / 256, 256, 0, stream>>>(cnt, gsum, gcnt, n, ng * 64, ng);
  k_count<<<(e + 255) / 256, 256, 0, stream>>>(dst, cnt, e);
  k_scanA<<<nb, 256, 0, stream>>>(cnt, startArr, bsum, n);
  k_scanB<<<1, 256, 0, stream>>>(bsum, nb);
  k_scanC<<<(n + 255) / 256, 256, 0, stream>>>(startArr, cursor, bsum, cnt, dinv, n);
  k_place<<<(e + 255) / 256, 256, 0, stream>>>(src, dst, cursor, csr, e);

  // Layer 1: A = x@W1 ; B = relu(agg(A) + b1)
  k_gemm64<<<(n + 63) / 64, 256, 0, stream>>>(x, W1, A, n);
  k_agg_relu<<<((size_t)n * 64 + 255) / 256, 256, 0, stream>>>(A, csr, startArr, cnt,
                                                               dinv, b1, B, n);
  // Layer 2: A = B@W2 ; pool(agg(A) + b2)
  k_gemm64<<<(n + 63) / 64, 256, 0, stream>>>(B, W2, A, n);
  k_agg_pool<<<((size_t)n * 64 + 255) / 256, 256, 0, stream>>>(A, csr, startArr, cnt,
                                                               dinv, b2, batch, gsum,
                                                               gcnt, n);
  // Head
  k_head<<<((size_t)ng * 64 + 255) / 256, 256, 0, stream>>>(gsum, gcnt, W3, b3, W4,
                                                            b4, out, ng);
}

// Round 2
// 616.988 us; speedup vs baseline: 1.2857x; 1.2857x over previous
//
#include <hip/hip_runtime.h>
#include <math.h>

// ---------------------------------------------------------------------------
// GCN: h1 = relu(norm_agg(x@W1)+b1); h2 = norm_agg(h1@W2)+b2;
//      g = mean_pool(h2, batch); out = relu(g@W3+b3)@W4 + b4
// norm_agg(h)[d] = (sum_{e: dst=d} h[src]*dinv[src] + h[d]*dinv[d]) * dinv[d]
// Strategy: CSR once (count->scan->place); GEMM epilogue pre-scales rows by
// dinv[row] so aggregation is a pure gather-sum (1 load chain, unroll 8 for
// MLP); pooling fused into layer-2 aggregation.
// ---------------------------------------------------------------------------

__global__ __launch_bounds__(256) void k_zero(int* cnt, float* gsum, float* gcnt,
                                              int n, int gsz, int ng) {
  int i = blockIdx.x * 256 + threadIdx.x;
  if (i < n) cnt[i] = 0;
  if (i < gsz) gsum[i] = 0.f;
  if (i < ng) gcnt[i] = 0.f;
}

__global__ __launch_bounds__(256) void k_count(const int* __restrict__ dst,
                                               int* __restrict__ cnt, int e) {
  int i = blockIdx.x * 256 + threadIdx.x;
  if (i < e) atomicAdd(&cnt[dst[i]], 1);
}

// Exclusive scan, level A: each block scans a 1024-element chunk.
__global__ __launch_bounds__(256) void k_scanA(const int* __restrict__ cnt,
                                               int* __restrict__ startArr,
                                               int* __restrict__ bsum, int n) {
  __shared__ int sh[256];
  int t = threadIdx.x, b = blockIdx.x;
  int base = b * 1024 + t * 4;
  int v0 = 0, v1 = 0, v2 = 0, v3 = 0;
  if (base + 3 < n) {
    int4 v = *(const int4*)&cnt[base];
    v0 = v.x; v1 = v.y; v2 = v.z; v3 = v.w;
  } else {
    if (base + 0 < n) v0 = cnt[base + 0];
    if (base + 1 < n) v1 = cnt[base + 1];
    if (base + 2 < n) v2 = cnt[base + 2];
  }
  int local = v0 + v1 + v2 + v3;
  sh[t] = local;
  __syncthreads();
  for (int off = 1; off < 256; off <<= 1) {
    int x = (t >= off) ? sh[t - off] : 0;
    __syncthreads();
    sh[t] += x;
    __syncthreads();
  }
  int excl = sh[t] - local;
  if (t == 255) bsum[b] = sh[255];
  if (base + 0 < n) startArr[base + 0] = excl;
  if (base + 1 < n) startArr[base + 1] = excl + v0;
  if (base + 2 < n) startArr[base + 2] = excl + v0 + v1;
  if (base + 3 < n) startArr[base + 3] = excl + v0 + v1 + v2;
}

// Level B: single block scans the (<=256) chunk totals, in place, exclusive.
__global__ __launch_bounds__(256) void k_scanB(int* __restrict__ bsum, int nb) {
  __shared__ int sh[256];
  int t = threadIdx.x;
  int v = (t < nb) ? bsum[t] : 0;
  sh[t] = v;
  __syncthreads();
  for (int off = 1; off < 256; off <<= 1) {
    int x = (t >= off) ? sh[t - off] : 0;
    __syncthreads();
    sh[t] += x;
    __syncthreads();
  }
  if (t < nb) bsum[t] = sh[t] - v;
}

// Level C: add chunk offsets; init cursor; compute dinv = 1/sqrt(deg+1).
__global__ __launch_bounds__(256) void k_scanC(int* __restrict__ startArr,
                                               int* __restrict__ cursor,
                                               const int* __restrict__ bsum,
                                               const int* __restrict__ cnt,
                                               float* __restrict__ dinv, int n) {
  int i = blockIdx.x * 256 + threadIdx.x;
  if (i >= n) return;
  int s = startArr[i] + bsum[i >> 10];
  startArr[i] = s;
  cursor[i] = s;
  dinv[i] = 1.0f / sqrtf((float)(cnt[i] + 1));
}

__global__ __launch_bounds__(256) void k_place(const int* __restrict__ src,
                                               const int* __restrict__ dst,
                                               int* __restrict__ cursor,
                                               int* __restrict__ csr, int e) {
  int i = blockIdx.x * 256 + threadIdx.x;
  if (i >= e) return;
  int d = dst[i];
  int pos = atomicAdd(&cursor[d], 1);
  csr[pos] = src[i];
}

// Y[N,64] = (X[N,64] @ W[64,64]) * dinv[row]  (row-scaled epilogue).
// Thread t: rows rb..rb+3 (rb=(t>>4)*4), cols c4..c4+3 (c4=(t&15)*4).
__global__ __launch_bounds__(256) void k_gemm64s(const float* __restrict__ X,
                                                 const float* __restrict__ W,
                                                 const float* __restrict__ dinv,
                                                 float* __restrict__ Y, int n) {
  __shared__ float Xs[64 * 65];
  __shared__ float Ws[64 * 64];
  int t = threadIdx.x;
  int r0 = blockIdx.x << 6;
  for (int i = t * 4; i < 4096; i += 1024)
    *(float4*)&Ws[i] = *(const float4*)&W[i];
  for (int s = t; s < 1024; s += 256) {
    int r = s >> 4, c4 = (s & 15) << 2;
    float4 v = make_float4(0.f, 0.f, 0.f, 0.f);
    if (r0 + r < n) v = *(const float4*)&X[(size_t)(r0 + r) * 64 + c4];
    Xs[r * 65 + c4 + 0] = v.x;
    Xs[r * 65 + c4 + 1] = v.y;
    Xs[r * 65 + c4 + 2] = v.z;
    Xs[r * 65 + c4 + 3] = v.w;
  }
  __syncthreads();
  int c4 = (t & 15) << 2;
  int rb = (t >> 4) << 2;
  float4 a0 = {0, 0, 0, 0}, a1 = {0, 0, 0, 0}, a2 = {0, 0, 0, 0}, a3 = {0, 0, 0, 0};
  for (int k = 0; k < 64; ++k) {
    float4 w = *(const float4*)&Ws[k * 64 + c4];
    float x0 = Xs[(rb + 0) * 65 + k];
    float x1 = Xs[(rb + 1) * 65 + k];
    float x2 = Xs[(rb + 2) * 65 + k];
    float x3 = Xs[(rb + 3) * 65 + k];
    a0.x += x0 * w.x; a0.y += x0 * w.y; a0.z += x0 * w.z; a0.w += x0 * w.w;
    a1.x += x1 * w.x; a1.y += x1 * w.y; a1.z += x1 * w.z; a1.w += x1 * w.w;
    a2.x += x2 * w.x; a2.y += x2 * w.y; a2.z += x2 * w.z; a2.w += x2 * w.w;
    a3.x += x3 * w.x; a3.y += x3 * w.y; a3.z += x3 * w.z; a3.w += x3 * w.w;
  }
  int r = r0 + rb;
  if (r + 0 < n) {
    float s0 = dinv[r + 0];
    a0.x *= s0; a0.y *= s0; a0.z *= s0; a0.w *= s0;
    *(float4*)&Y[(size_t)(r + 0) * 64 + c4] = a0;
  }
  if (r + 1 < n) {
    float s1 = dinv[r + 1];
    a1.x *= s1; a1.y *= s1; a1.z *= s1; a1.w *= s1;
    *(float4*)&Y[(size_t)(r + 1) * 64 + c4] = a1;
  }
  if (r + 2 < n) {
    float s2 = dinv[r + 2];
    a2.x *= s2; a2.y *= s2; a2.z *= s2; a2.w *= s2;
    *(float4*)&Y[(size_t)(r + 2) * 64 + c4] = a2;
  }
  if (r + 3 < n) {
    float s3 = dinv[r + 3];
    a3.x *= s3; a3.y *= s3; a3.z *= s3; a3.w *= s3;
    *(float4*)&Y[(size_t)(r + 3) * 64 + c4] = a3;
  }
}

// Gather-sum over pre-scaled rows Hs; unroll 8 with predicated tail for MLP.
// acc = (Hs[d] + sum_e Hs[src_e]) * dinv[d] + bias  [then relu / pool].
__device__ __forceinline__ float agg_row(const float* __restrict__ Hs,
                                         const int* __restrict__ csr,
                                         int p0, int c, int wid, int lane) {
  float acc = Hs[(size_t)wid * 64 + lane];
  int p_end = p0 + c;
  for (int p = p0; p < p_end; p += 8) {
#pragma unroll
    for (int j = 0; j < 8; ++j) {
      int q = p + j;
      int qc = q < p_end ? q : (p_end - 1);
      float v = Hs[(size_t)csr[qc] * 64 + lane];
      acc += (q < p_end) ? v : 0.f;
    }
  }
  return acc;
}

// Layer-1 aggregation: one wave per node, lane = feature; out = relu(agg + b).
__global__ __launch_bounds__(256) void k_agg_relu(
    const float* __restrict__ Hs, const int* __restrict__ csr,
    const int* __restrict__ startArr, const int* __restrict__ cnt,
    const float* __restrict__ dinv, const float* __restrict__ bias,
    float* __restrict__ out, int n) {
  int wid = (blockIdx.x * 256 + threadIdx.x) >> 6;
  int lane = threadIdx.x & 63;
  if (wid >= n) return;
  float acc = agg_row(Hs, csr, startArr[wid], cnt[wid], wid, lane);
  acc = acc * dinv[wid] + bias[lane];
  out[(size_t)wid * 64 + lane] = fmaxf(acc, 0.f);
}

// Layer-2 aggregation fused with mean-pool accumulation.
__global__ __launch_bounds__(256) void k_agg_pool(
    const float* __restrict__ Hs, const int* __restrict__ csr,
    const int* __restrict__ startArr, const int* __restrict__ cnt,
    const float* __restrict__ dinv, const float* __restrict__ bias,
    const int* __restrict__ batch, float* __restrict__ gsum,
    float* __restrict__ gcnt, int n) {
  int wid = (blockIdx.x * 256 + threadIdx.x) >> 6;
  int lane = threadIdx.x & 63;
  if (wid >= n) return;
  float acc = agg_row(Hs, csr, startArr[wid], cnt[wid], wid, lane);
  acc = acc * dinv[wid] + bias[lane];
  int g = batch[wid];
  atomicAdd(&gsum[(size_t)g * 64 + lane], acc);
  if (lane == 0) atomicAdd(&gcnt[g], 1.0f);
}

// Head: per-graph wave: m = gsum/max(cnt,1); t = relu(m@W3+b3); out = t.W4+b4
__global__ __launch_bounds__(256) void k_head(
    const float* __restrict__ gsum, const float* __restrict__ gcnt,
    const float* __restrict__ W3, const float* __restrict__ b3,
    const float* __restrict__ W4, const float* __restrict__ b4,
    float* __restrict__ out, int ng) {
  int wid = (blockIdx.x * 256 + threadIdx.x) >> 6;
  int lane = threadIdx.x & 63;
  if (wid >= ng) return;
  float cden = fmaxf(gcnt[wid], 1.0f);
  float m = gsum[(size_t)wid * 64 + lane] / cden;
  float acc = b3[lane];
  for (int k = 0; k < 64; ++k) {
    float mk = __shfl(m, k);
    acc += mk * W3[k * 64 + lane];
  }
  acc = fmaxf(acc, 0.f);
  float r = acc * W4[lane];
  for (int off = 32; off; off >>= 1) r += __shfl_down(r, off);
  if (lane == 0) out[wid] = r + b4[0];
}

extern "C" void kernel_launch(void* const* d_in, const int* in_sizes, int n_in,
                              void* d_out, int out_size, void* d_ws, size_t ws_size,
                              hipStream_t stream) {
  const float* x = (const float*)d_in[0];
  const int* edge = (const int*)d_in[1];   // [2, E] int32
  const int* batch = (const int*)d_in[2];  // [N] int32, sorted
  const float* W1 = (const float*)d_in[3];
  const float* b1 = (const float*)d_in[4];
  const float* W2 = (const float*)d_in[5];
  const float* b2 = (const float*)d_in[6];
  const float* W3 = (const float*)d_in[7];
  const float* b3 = (const float*)d_in[8];
  const float* W4 = (const float*)d_in[9];
  const float* b4 = (const float*)d_in[10];
  float* out = (float*)d_out;

  const int n = in_sizes[0] / 64;   // 100000
  const int e = in_sizes[1] / 2;    // 1600000
  const int ng = out_size;          // 512
  const int* src = edge;
  const int* dst = edge + e;

  // Workspace layout (~59.4 MB total).
  char* ws = (char*)d_ws;
  size_t off = 0;
  auto alloc = [&](size_t bytes) -> void* {
    void* p = ws + off;
    off = (off + bytes + 255) & ~(size_t)255;
    return p;
  };
  float* A = (float*)alloc((size_t)n * 64 * 4);      // Hs (scaled gemm output)
  float* B = (float*)alloc((size_t)n * 64 * 4);      // aggregated / relu
  float* dinv = (float*)alloc((size_t)n * 4);
  int* cnt = (int*)alloc((size_t)n * 4);
  int* startArr = (int*)alloc((size_t)n * 4);
  int* cursor = (int*)alloc((size_t)n * 4);
  int* bsum = (int*)alloc(1024);
  int* csr = (int*)alloc((size_t)e * 4);
  float* gsum = (float*)alloc((size_t)ng * 64 * 4);
  float* gcnt = (float*)alloc((size_t)ng * 4);

  const int nb = (n + 1023) / 1024;  // scan chunks (98)

  int zmax = n;
  if (ng * 64 > zmax) zmax = ng * 64;
  k_zero<<<(zmax + 255) / 256, 256, 0, stream>>>(cnt, gsum, gcnt, n, ng * 64, ng);
  k_count<<<(e + 255) / 256, 256, 0, stream>>>(dst, cnt, e);
  k_scanA<<<nb, 256, 0, stream>>>(cnt, startArr, bsum, n);
  k_scanB<<<1, 256, 0, stream>>>(bsum, nb);
  k_scanC<<<(n + 255) / 256, 256, 0, stream>>>(startArr, cursor, bsum, cnt, dinv, n);
  k_place<<<(e + 255) / 256, 256, 0, stream>>>(src, dst, cursor, csr, e);

  // Layer 1: A = (x@W1)*dinv ; B = relu(agg(A)*dinv + b1)
  k_gemm64s<<<(n + 63) / 64, 256, 0, stream>>>(x, W1, dinv, A, n);
  k_agg_relu<<<((size_t)n * 64 + 255) / 256, 256, 0, stream>>>(A, csr, startArr, cnt,
                                                               dinv, b1, B, n);
  // Layer 2: A = (B@W2)*dinv ; pool(agg(A)*dinv + b2)
  k_gemm64s<<<(n + 63) / 64, 256, 0, stream>>>(B, W2, dinv, A, n);
  k_agg_pool<<<((size_t)n * 64 + 255) / 256, 256, 0, stream>>>(A, csr, startArr, cnt,
                                                               dinv, b2, batch, gsum,
                                                               gcnt, n);
  // Head
  k_head<<<((size_t)ng * 64 + 255) / 256, 256, 0, stream>>>(gsum, gcnt, W3, b3, W4,
                                                            b4, out, ng);
}